// Round 7
// baseline (376.253 us; speedup 1.0000x reference)
//
#include <hip/hip_runtime.h>
#include <hip/hip_fp16.h>

#define NFEAT 128

typedef _Float16 v8hf __attribute__((ext_vector_type(8)));
typedef _Float16 v4hf __attribute__((ext_vector_type(4)));
typedef float v4f __attribute__((ext_vector_type(4)));

// ------- degree histogram + per-edge rank (incl. self edges) + W prep --------
// rank aliases hB (dead until agg1), NOT g16, so GEMM1 can overlap scatter.
__global__ void k_deg_rank_w(const int* __restrict__ dst, int* __restrict__ deg,
                             int* __restrict__ rank, int E, int N,
                             const float* __restrict__ W1, const float* __restrict__ W2,
                             _Float16* __restrict__ Wt1, _Float16* __restrict__ Wt2) {
  int e = blockIdx.x * blockDim.x + threadIdx.x;
  if (e < E) rank[e] = atomicAdd(&deg[dst[e]], 1);
  else if (e < E + N) rank[e] = atomicAdd(&deg[e - E], 1);
  else if (e < E + N + 32768) {
    int idx = e - E - N;             // 0..32767
    const float* W = (idx < 16384) ? W1 : W2;
    _Float16* Wt = (idx < 16384) ? Wt1 : Wt2;
    int i = idx & 16383;
    int k = i >> 7, n = i & 127;
    Wt[n * 128 + k] = (_Float16)W[k * 128 + n];
  }
}

// ---------------- wave-level inclusive scan (shuffle ladder) -----------------
__device__ __forceinline__ int wave_incl_scan(int v, int lane) {
  #pragma unroll
  for (int off = 1; off < 64; off <<= 1) {
    int t = __shfl_up(v, off, 64);
    if (lane >= off) v += t;
  }
  return v;
}

// ---- shallow scan over 512 elems / 256-thread block; also emits dinv --------
// base[] stays chunk-local; consumers add partials[i>>9] (final scan of chunk
// totals) themselves -> no separate finalize pass over N.
__global__ __launch_bounds__(256) void k_scan_blocks(const int* __restrict__ deg,
    int* __restrict__ base, int* __restrict__ partials,
    float* __restrict__ dinv, int n) {
  __shared__ int lds[4];
  const int tid = threadIdx.x;
  const int lane = tid & 63;
  const int wv = tid >> 6;
  int i0 = (blockIdx.x << 9) + (tid << 1);
  int a = (i0 < n) ? deg[i0] : 0;
  int b = (i0 + 1 < n) ? deg[i0 + 1] : 0;
  if (i0 < n) dinv[i0] = rsqrtf((float)a);        // deg includes self-loop
  if (i0 + 1 < n) dinv[i0 + 1] = rsqrtf((float)b);
  int inc = wave_incl_scan(a + b, lane);
  if (lane == 63) lds[wv] = inc;
  __syncthreads();
  int woff = 0, tot = 0;
  #pragma unroll
  for (int w = 0; w < 4; w++) {
    int t = lds[w];
    tot += t;
    if (w < wv) woff += t;
  }
  int ex = woff + inc - (a + b);
  const int N1 = n + 1;
  if (i0 < N1) base[i0] = ex;
  if (i0 + 1 < N1) base[i0 + 1] = ex + a;
  if (tid == 255) partials[blockIdx.x] = tot;
}

__global__ __launch_bounds__(256) void k_scan_partials(int* __restrict__ partials,
                                                       int nb) {
  __shared__ int lds[4];
  const int tid = threadIdx.x;
  const int lane = tid & 63;
  const int wv = tid >> 6;
  int v = (tid < nb) ? partials[tid] : 0;
  int inc = wave_incl_scan(v, lane);
  if (lane == 63) lds[wv] = inc;
  __syncthreads();
  int woff = 0;
  #pragma unroll
  for (int w = 0; w < 4; w++) if (w < wv) woff += lds[w];
  if (tid < nb) partials[tid] = woff + inc - v;
}

// ---------------- MFMA fp16 GEMM tile: g16[r][:] = half((A[r][:]@W)*dinv[r]) -
template <typename AT>
__device__ __forceinline__ void gemm_tile(
    const AT* __restrict__ A, const _Float16* __restrict__ Wt,
    const float* __restrict__ dinv, _Float16* __restrict__ g16, int N, int tile,
    _Float16 (*As)[136], _Float16 (*Ws)[136]) {
  const int tid = threadIdx.x;
  const int row0 = tile * 64;

  if constexpr (sizeof(AT) == 4) {   // fp32 input: load + cast + packed 8B write
    #pragma unroll
    for (int i = 0; i < 8; i++) {
      int idx = tid + i * 256;       // 0..2047
      int row = idx >> 5;
      int c4 = idx & 31;
      int gr = row0 + row; gr = (gr < N) ? gr : (N - 1);
      float4 v = *(const float4*)((const float*)A + (size_t)gr * NFEAT + c4 * 4);
      v4hf h;
      h[0] = (_Float16)v.x; h[1] = (_Float16)v.y;
      h[2] = (_Float16)v.z; h[3] = (_Float16)v.w;
      *(v4hf*)&As[row][c4 * 4] = h;
    }
  } else {                           // fp16 input: straight 16B copies
    #pragma unroll
    for (int i = 0; i < 4; i++) {
      int idx = tid + i * 256;
      int row = idx >> 4;
      int c8 = idx & 15;
      int gr = row0 + row; gr = (gr < N) ? gr : (N - 1);
      *(uint4*)&As[row][c8 * 8] =
          *(const uint4*)((const _Float16*)A + (size_t)gr * NFEAT + c8 * 8);
    }
  }
  #pragma unroll
  for (int i = 0; i < 8; i++) {
    int idx = tid + i * 256;
    int row = idx >> 4;
    int c8 = idx & 15;
    *(uint4*)&Ws[row][c8 * 8] = *(const uint4*)(Wt + (size_t)row * 128 + c8 * 8);
  }
  __syncthreads();

  const int wv = tid >> 6;
  const int lane = tid & 63;
  const int m = lane & 15;
  const int q = lane >> 4;

  v4f acc[8] = {};
  const _Float16* arow = &As[wv * 16 + m][0];
  #pragma unroll
  for (int kt = 0; kt < 4; kt++) {
    v8hf af = *(const v8hf*)(arow + kt * 32 + q * 8);
    #pragma unroll
    for (int ct = 0; ct < 8; ct++) {
      v8hf bf = *(const v8hf*)(&Ws[ct * 16 + m][kt * 32 + q * 8]);
      acc[ct] = __builtin_amdgcn_mfma_f32_16x16x32_f16(af, bf, acc[ct], 0, 0, 0);
    }
  }

  float dv[4];
  #pragma unroll
  for (int r = 0; r < 4; r++) {
    int nd = row0 + wv * 16 + q * 4 + r;
    int c = (nd < N) ? nd : (N - 1);
    dv[r] = dinv[c];
  }

  __syncthreads();                   // all As reads complete -> reuse as C tile
  #pragma unroll
  for (int ct = 0; ct < 8; ct++)
    #pragma unroll
    for (int r = 0; r < 4; r++)
      As[wv * 16 + q * 4 + r][ct * 16 + m] = (_Float16)(acc[ct][r] * dv[r]);
  __syncthreads();

  #pragma unroll
  for (int i = 0; i < 4; i++) {
    int idx = tid + i * 256;         // 0..1023
    int row = idx >> 4;
    int c8 = idx & 15;
    int gr = row0 + row;
    if (gr < N)
      *(v8hf*)(g16 + (size_t)gr * NFEAT + c8 * 8) = *(const v8hf*)&As[row][c8 * 8];
  }
}

// -------- fused: scatter (independent) interleaved with layer-1 GEMM ---------
// Blocks [0,2*gg): odd -> GEMM tile id>>1, even -> scatter block id>>1.
// Blocks [2*gg, scb+gg): scatter block id-gg. GEMM work hides under scatter.
__global__ __launch_bounds__(256) void k_sg1(
    const int* __restrict__ src, const int* __restrict__ dst,
    const int* __restrict__ rank, const int* __restrict__ base,
    const int* __restrict__ partials, int* __restrict__ ssrc,
    const float* __restrict__ x, const _Float16* __restrict__ Wt1,
    const float* __restrict__ dinv, _Float16* __restrict__ g16,
    int E, int N, int gg) {
  __shared__ _Float16 As[64][136];
  __shared__ _Float16 Ws[128][136];
  int id = blockIdx.x;
  if (id < 2 * gg && (id & 1)) {
    int tile = id >> 1;
    if (tile == 0 && threadIdx.x < 16) {   // zero sentinel row N
      v8hf z;
      #pragma unroll
      for (int j = 0; j < 8; j++) z[j] = (_Float16)0.f;
      *(v8hf*)(g16 + (size_t)N * NFEAT + threadIdx.x * 8) = z;
    }
    gemm_tile<float>(x, Wt1, dinv, g16, N, tile, As, Ws);
    return;
  }
  id = (id < 2 * gg) ? (id >> 1) : (id - gg);
  int e = id * 256 + threadIdx.x;
  if (e < E) {
    int d = dst[e];
    ssrc[base[d] + partials[d >> 9] + rank[e]] = src[e];
  } else if (e < E + N) {
    int nn = e - E;
    ssrc[base[nn] + partials[nn >> 9] + rank[e]] = nn;
  }
}

// ---------------- layer-2 GEMM (standalone) ----------------------------------
__global__ __launch_bounds__(256) void k_gemm2(
    const _Float16* __restrict__ A, const _Float16* __restrict__ Wt,
    const float* __restrict__ dinv, _Float16* __restrict__ g16, int N) {
  __shared__ _Float16 As[64][136];
  __shared__ _Float16 Ws[128][136];
  gemm_tile<_Float16>(A, Wt, dinv, g16, N, blockIdx.x, As, Ws);
}

// ---------------- agg: wave per node, depth-2 pipelined gathers --------------
__global__ __launch_bounds__(256) void k_agg(
    const _Float16* __restrict__ g, const float* __restrict__ dinv,
    const int* __restrict__ base, const int* __restrict__ partials,
    const int* __restrict__ ssrc,
    const float* __restrict__ bias, _Float16* __restrict__ hB, int N) {
  const int lane = threadIdx.x & 63;
  const int n = blockIdx.x * 4 + (threadIdx.x >> 6);
  if (n >= N) return;
  const int gq = lane >> 4;
  const int l = lane & 15;
  const int b0 = base[n] + partials[n >> 9];
  const int b1 = base[n + 1] + partials[(n + 1) >> 9];

  int e = b0;
  int p0 = e + gq, p1 = e + 4 + gq;
  int i0 = ssrc[p0], i1 = ssrc[p1];          // +8 slack makes loads safe
  i0 = (p0 < b1) ? i0 : N;
  i1 = (p1 < b1) ? i1 : N;
  v8hf r0 = *(const v8hf*)(g + (size_t)i0 * NFEAT + l * 8);
  v8hf r1 = *(const v8hf*)(g + (size_t)i1 * NFEAT + l * 8);
  int e2 = e + 8;
  int j0 = N, j1 = N;
  if (e2 < b1) {
    int q0 = e2 + gq, q1 = e2 + 4 + gq;
    j0 = ssrc[q0]; j1 = ssrc[q1];
    j0 = (q0 < b1) ? j0 : N;
    j1 = (q1 < b1) ? j1 : N;
  }

  float acc[8] = {};
  while (true) {
    bool more = (e2 < b1);
    v8hf s0, s1;
    if (more) {                       // issue iter k+1 gathers before consuming k
      s0 = *(const v8hf*)(g + (size_t)j0 * NFEAT + l * 8);
      s1 = *(const v8hf*)(g + (size_t)j1 * NFEAT + l * 8);
    }
    int e3 = e2 + 8;
    int c0 = N, c1 = N;
    if (e3 < b1) {                    // iter k+2 indices
      int q0 = e3 + gq, q1 = e3 + 4 + gq;
      c0 = ssrc[q0]; c1 = ssrc[q1];
      c0 = (q0 < b1) ? c0 : N;
      c1 = (q1 < b1) ? c1 : N;
    }
    #pragma unroll
    for (int j = 0; j < 8; j++) acc[j] += (float)r0[j] + (float)r1[j];
    if (!more) break;
    r0 = s0; r1 = s1;
    j0 = c0; j1 = c1;
    e2 = e3;
  }

  #pragma unroll
  for (int j = 0; j < 8; j++) {
    acc[j] += __shfl_xor(acc[j], 16, 64);
    acc[j] += __shfl_xor(acc[j], 32, 64);
  }
  if (gq == 0) {
    float dvn = dinv[n];
    const float* bp = bias + l * 8;
    float4 bb0 = *(const float4*)(bp);
    float4 bb1 = *(const float4*)(bp + 4);
    float bv[8] = {bb0.x, bb0.y, bb0.z, bb0.w, bb1.x, bb1.y, bb1.z, bb1.w};
    v8hf o;
    #pragma unroll
    for (int j = 0; j < 8; j++)
      o[j] = (_Float16)fmaxf(acc[j] * dvn + bv[j], 0.f);
    *(v8hf*)(hB + (size_t)n * NFEAT + l * 8) = o;
  }
}

// ---------------- layer-2 agg fused with final linear (same pipeline) --------
__global__ __launch_bounds__(256) void k_agg_final(
    const _Float16* __restrict__ g, const float* __restrict__ dinv,
    const int* __restrict__ base, const int* __restrict__ partials,
    const int* __restrict__ ssrc,
    const float* __restrict__ bias, const float* __restrict__ wlin,
    const float* __restrict__ blin, float* __restrict__ out, int N) {
  const int lane = threadIdx.x & 63;
  const int n = blockIdx.x * 4 + (threadIdx.x >> 6);
  if (n >= N) return;
  const int gq = lane >> 4;
  const int l = lane & 15;
  const int b0 = base[n] + partials[n >> 9];
  const int b1 = base[n + 1] + partials[(n + 1) >> 9];

  int e = b0;
  int p0 = e + gq, p1 = e + 4 + gq;
  int i0 = ssrc[p0], i1 = ssrc[p1];
  i0 = (p0 < b1) ? i0 : N;
  i1 = (p1 < b1) ? i1 : N;
  v8hf r0 = *(const v8hf*)(g + (size_t)i0 * NFEAT + l * 8);
  v8hf r1 = *(const v8hf*)(g + (size_t)i1 * NFEAT + l * 8);
  int e2 = e + 8;
  int j0 = N, j1 = N;
  if (e2 < b1) {
    int q0 = e2 + gq, q1 = e2 + 4 + gq;
    j0 = ssrc[q0]; j1 = ssrc[q1];
    j0 = (q0 < b1) ? j0 : N;
    j1 = (q1 < b1) ? j1 : N;
  }

  float acc[8] = {};
  while (true) {
    bool more = (e2 < b1);
    v8hf s0, s1;
    if (more) {
      s0 = *(const v8hf*)(g + (size_t)j0 * NFEAT + l * 8);
      s1 = *(const v8hf*)(g + (size_t)j1 * NFEAT + l * 8);
    }
    int e3 = e2 + 8;
    int c0 = N, c1 = N;
    if (e3 < b1) {
      int q0 = e3 + gq, q1 = e3 + 4 + gq;
      c0 = ssrc[q0]; c1 = ssrc[q1];
      c0 = (q0 < b1) ? c0 : N;
      c1 = (q1 < b1) ? c1 : N;
    }
    #pragma unroll
    for (int j = 0; j < 8; j++) acc[j] += (float)r0[j] + (float)r1[j];
    if (!more) break;
    r0 = s0; r1 = s1;
    j0 = c0; j1 = c1;
    e2 = e3;
  }

  #pragma unroll
  for (int j = 0; j < 8; j++) {
    acc[j] += __shfl_xor(acc[j], 16, 64);
    acc[j] += __shfl_xor(acc[j], 32, 64);
  }
  float dvn = dinv[n];
  const float* bp = bias + l * 8;
  const float* wp = wlin + l * 8;
  float4 bb0 = *(const float4*)(bp);
  float4 bb1 = *(const float4*)(bp + 4);
  float4 wl0 = *(const float4*)(wp);
  float4 wl1 = *(const float4*)(wp + 4);
  float bv[8] = {bb0.x, bb0.y, bb0.z, bb0.w, bb1.x, bb1.y, bb1.z, bb1.w};
  float wv[8] = {wl0.x, wl0.y, wl0.z, wl0.w, wl1.x, wl1.y, wl1.z, wl1.w};
  float pv = 0.f;
  #pragma unroll
  for (int j = 0; j < 8; j++)
    pv += fmaxf(acc[j] * dvn + bv[j], 0.f) * wv[j];
  pv += __shfl_xor(pv, 1, 64);
  pv += __shfl_xor(pv, 2, 64);
  pv += __shfl_xor(pv, 4, 64);
  pv += __shfl_xor(pv, 8, 64);
  if (lane == 0) out[n] = pv + blin[0];
}

extern "C" void kernel_launch(void* const* d_in, const int* in_sizes, int n_in,
                              void* d_out, int out_size, void* d_ws, size_t ws_size,
                              hipStream_t stream) {
  const float* x    = (const float*)d_in[0];
  const int*   ei   = (const int*)d_in[1];
  const float* W1   = (const float*)d_in[2];
  const float* b1   = (const float*)d_in[3];
  const float* W2   = (const float*)d_in[4];
  const float* b2   = (const float*)d_in[5];
  const float* Wlin = (const float*)d_in[6];
  const float* blin = (const float*)d_in[7];
  const int N = in_sizes[0] / NFEAT;
  const int E = in_sizes[1] / 2;
  const int* src = ei;
  const int* dst = ei + E;
  const int Etot = E + N;   // real edges + self edges

  // workspace layout (4B units)
  int* ws_i = (int*)d_ws;
  size_t off = 0;
  int* deg      = ws_i + off; off += N;
  int* base     = ws_i + off; off += (size_t)N + 1;
  off = (off + 3) & ~(size_t)3;
  int* partials = ws_i + off; off += 256;
  int* ssrc     = ws_i + off; off += Etot + 8;   // +8 slack for tail loads
  float* dinv   = (float*)(ws_i + off); off += N;
  off = (off + 3) & ~(size_t)3;
  _Float16* Wt1 = (_Float16*)(ws_i + off); off += 8192;  // 16384 halves = 8192 words
  _Float16* Wt2 = (_Float16*)(ws_i + off); off += 8192;
  _Float16* g16 = (_Float16*)(ws_i + off); off += (size_t)(N + 1) * 64;  // +sentinel
  _Float16* hB  = (_Float16*)(ws_i + off); off += (size_t)N * 64;
  // rank aliases hB: written by k_deg_rank_w, consumed by k_sg1's scatter half,
  // dead before agg1 writes hB. Does NOT alias g16 (GEMM1 runs inside k_sg1).
  int* rank = (int*)hB;

  hipMemsetAsync(deg, 0, (size_t)N * sizeof(int), stream);

  const int tpbE = 256;
  const int gE = (Etot + 32768 + tpbE - 1) / tpbE;
  k_deg_rank_w<<<gE, tpbE, 0, stream>>>(dst, deg, rank, E, N, W1, W2, Wt1, Wt2);

  const int nb = (N + 1 + 511) / 512;
  k_scan_blocks<<<nb, 256, 0, stream>>>(deg, base, partials, dinv, N);
  k_scan_partials<<<1, 256, 0, stream>>>(partials, nb);

  const int gg = (N + 63) / 64;
  const int ga = (N + 3) / 4;
  const int scb = (Etot + 255) / 256;
  // fused: scatter + layer-1 GEMM, interleaved for true overlap
  k_sg1<<<scb + gg, 256, 0, stream>>>(src, dst, rank, base, partials, ssrc,
                                      x, Wt1, dinv, g16, E, N, gg);
  // layer-1 agg
  k_agg<<<ga, 256, 0, stream>>>(g16, dinv, base, partials, ssrc, b1, hB, N);
  // layer 2
  k_gemm2<<<gg, 256, 0, stream>>>(hB, Wt2, dinv, g16, N);
  k_agg_final<<<ga, 256, 0, stream>>>(g16, dinv, base, partials, ssrc, b2,
                                      Wlin, blin, (float*)d_out, N);
}

// Round 8
// 374.802 us; speedup vs baseline: 1.0039x; 1.0039x over previous
//
#include <hip/hip_runtime.h>
#include <hip/hip_fp16.h>

#define NFEAT 128

typedef _Float16 v8hf __attribute__((ext_vector_type(8)));
typedef _Float16 v4hf __attribute__((ext_vector_type(4)));
typedef float v4f __attribute__((ext_vector_type(4)));

// ------- degree histogram + per-edge rank (incl. self edges) + W prep --------
// rank aliases bufB (dead until agg1 writes bufB), NOT bufA, so GEMM1 can
// overlap scatter inside k_sg1.
__global__ void k_deg_rank_w(const int* __restrict__ dst, int* __restrict__ deg,
                             int* __restrict__ rank, int E, int N,
                             const float* __restrict__ W1, const float* __restrict__ W2,
                             _Float16* __restrict__ Wt1, _Float16* __restrict__ Wt2) {
  int e = blockIdx.x * blockDim.x + threadIdx.x;
  if (e < E) rank[e] = atomicAdd(&deg[dst[e]], 1);
  else if (e < E + N) rank[e] = atomicAdd(&deg[e - E], 1);
  else if (e < E + N + 32768) {
    int idx = e - E - N;             // 0..32767
    const float* W = (idx < 16384) ? W1 : W2;
    _Float16* Wt = (idx < 16384) ? Wt1 : Wt2;
    int i = idx & 16383;
    int k = i >> 7, n = i & 127;
    Wt[n * 128 + k] = (_Float16)W[k * 128 + n];
  }
}

// ---------------- wave-level inclusive scan (shuffle ladder) -----------------
__device__ __forceinline__ int wave_incl_scan(int v, int lane) {
  #pragma unroll
  for (int off = 1; off < 64; off <<= 1) {
    int t = __shfl_up(v, off, 64);
    if (lane >= off) v += t;
  }
  return v;
}

// ---- shallow scan over 512 elems / 256-thread block; also emits dinv --------
// base[] stays chunk-local; consumers add partials[i>>9] themselves.
__global__ __launch_bounds__(256) void k_scan_blocks(const int* __restrict__ deg,
    int* __restrict__ base, int* __restrict__ partials,
    float* __restrict__ dinv, int n) {
  __shared__ int lds[4];
  const int tid = threadIdx.x;
  const int lane = tid & 63;
  const int wv = tid >> 6;
  int i0 = (blockIdx.x << 9) + (tid << 1);
  int a = (i0 < n) ? deg[i0] : 0;
  int b = (i0 + 1 < n) ? deg[i0 + 1] : 0;
  if (i0 < n) dinv[i0] = rsqrtf((float)a);        // deg includes self-loop
  if (i0 + 1 < n) dinv[i0 + 1] = rsqrtf((float)b);
  int inc = wave_incl_scan(a + b, lane);
  if (lane == 63) lds[wv] = inc;
  __syncthreads();
  int woff = 0, tot = 0;
  #pragma unroll
  for (int w = 0; w < 4; w++) {
    int t = lds[w];
    tot += t;
    if (w < wv) woff += t;
  }
  int ex = woff + inc - (a + b);
  const int N1 = n + 1;
  if (i0 < N1) base[i0] = ex;
  if (i0 + 1 < N1) base[i0 + 1] = ex + a;
  if (tid == 255) partials[blockIdx.x] = tot;
}

__global__ __launch_bounds__(256) void k_scan_partials(int* __restrict__ partials,
                                                       int nb) {
  __shared__ int lds[4];
  const int tid = threadIdx.x;
  const int lane = tid & 63;
  const int wv = tid >> 6;
  int v = (tid < nb) ? partials[tid] : 0;
  int inc = wave_incl_scan(v, lane);
  if (lane == 63) lds[wv] = inc;
  __syncthreads();
  int woff = 0;
  #pragma unroll
  for (int w = 0; w < 4; w++) if (w < wv) woff += lds[w];
  if (tid < nb) partials[tid] = woff + inc - v;
}

// ---------------- MFMA fp16 GEMM tile: out[r][:] = half((A[r][:]@W)*dinv[r]) -
template <typename AT>
__device__ __forceinline__ void gemm_tile(
    const AT* __restrict__ A, const _Float16* __restrict__ Wt,
    const float* __restrict__ dinv, _Float16* __restrict__ g16, int N, int tile,
    _Float16 (*As)[136], _Float16 (*Ws)[136]) {
  const int tid = threadIdx.x;
  const int row0 = tile * 64;

  if constexpr (sizeof(AT) == 4) {   // fp32 input: load + cast + packed 8B write
    #pragma unroll
    for (int i = 0; i < 8; i++) {
      int idx = tid + i * 256;       // 0..2047
      int row = idx >> 5;
      int c4 = idx & 31;
      int gr = row0 + row; gr = (gr < N) ? gr : (N - 1);
      float4 v = *(const float4*)((const float*)A + (size_t)gr * NFEAT + c4 * 4);
      v4hf h;
      h[0] = (_Float16)v.x; h[1] = (_Float16)v.y;
      h[2] = (_Float16)v.z; h[3] = (_Float16)v.w;
      *(v4hf*)&As[row][c4 * 4] = h;
    }
  } else {
    #pragma unroll
    for (int i = 0; i < 4; i++) {
      int idx = tid + i * 256;
      int row = idx >> 4;
      int c8 = idx & 15;
      int gr = row0 + row; gr = (gr < N) ? gr : (N - 1);
      *(uint4*)&As[row][c8 * 8] =
          *(const uint4*)((const _Float16*)A + (size_t)gr * NFEAT + c8 * 8);
    }
  }
  #pragma unroll
  for (int i = 0; i < 8; i++) {
    int idx = tid + i * 256;
    int row = idx >> 4;
    int c8 = idx & 15;
    *(uint4*)&Ws[row][c8 * 8] = *(const uint4*)(Wt + (size_t)row * 128 + c8 * 8);
  }
  __syncthreads();

  const int wv = tid >> 6;
  const int lane = tid & 63;
  const int m = lane & 15;
  const int q = lane >> 4;

  v4f acc[8] = {};
  const _Float16* arow = &As[wv * 16 + m][0];
  #pragma unroll
  for (int kt = 0; kt < 4; kt++) {
    v8hf af = *(const v8hf*)(arow + kt * 32 + q * 8);
    #pragma unroll
    for (int ct = 0; ct < 8; ct++) {
      v8hf bf = *(const v8hf*)(&Ws[ct * 16 + m][kt * 32 + q * 8]);
      acc[ct] = __builtin_amdgcn_mfma_f32_16x16x32_f16(af, bf, acc[ct], 0, 0, 0);
    }
  }

  float dv[4];
  #pragma unroll
  for (int r = 0; r < 4; r++) {
    int nd = row0 + wv * 16 + q * 4 + r;
    int c = (nd < N) ? nd : (N - 1);
    dv[r] = dinv[c];
  }

  __syncthreads();                   // all As reads complete -> reuse as C tile
  #pragma unroll
  for (int ct = 0; ct < 8; ct++)
    #pragma unroll
    for (int r = 0; r < 4; r++)
      As[wv * 16 + q * 4 + r][ct * 16 + m] = (_Float16)(acc[ct][r] * dv[r]);
  __syncthreads();

  #pragma unroll
  for (int i = 0; i < 4; i++) {
    int idx = tid + i * 256;         // 0..1023
    int row = idx >> 4;
    int c8 = idx & 15;
    int gr = row0 + row;
    if (gr < N)
      *(v8hf*)(g16 + (size_t)gr * NFEAT + c8 * 8) = *(const v8hf*)&As[row][c8 * 8];
  }
}

// -------- fused: scatter (independent) interleaved with layer-1 GEMM ---------
// Blocks [0,2*gg): odd -> GEMM tile id>>1, even -> scatter block id>>1.
// Blocks [2*gg, scb+gg): scatter block id-gg. GEMM work hides under scatter.
__global__ __launch_bounds__(256) void k_sg1(
    const int* __restrict__ src, const int* __restrict__ dst,
    const int* __restrict__ rank, const int* __restrict__ base,
    const int* __restrict__ partials, int* __restrict__ ssrc,
    const float* __restrict__ x, const _Float16* __restrict__ Wt1,
    const float* __restrict__ dinv, _Float16* __restrict__ gA,
    _Float16* __restrict__ gB, int E, int N, int gg) {
  __shared__ _Float16 As[64][136];
  __shared__ _Float16 Ws[128][136];
  int id = blockIdx.x;
  if (id < 2 * gg && (id & 1)) {
    int tile = id >> 1;
    if (tile == 0 && threadIdx.x < 32) {   // zero sentinel row N in BOTH buffers
      v8hf z;
      #pragma unroll
      for (int j = 0; j < 8; j++) z[j] = (_Float16)0.f;
      _Float16* p = (threadIdx.x < 16) ? gA : gB;
      *(v8hf*)(p + (size_t)N * NFEAT + (threadIdx.x & 15) * 8) = z;
    }
    gemm_tile<float>(x, Wt1, dinv, gA, N, tile, As, Ws);
    return;
  }
  id = (id < 2 * gg) ? (id >> 1) : (id - gg);
  int e = id * 256 + threadIdx.x;
  if (e < E) {
    int d = dst[e];
    ssrc[base[d] + partials[d >> 9] + rank[e]] = src[e];
  } else if (e < E + N) {
    int nn = e - E;
    ssrc[base[nn] + partials[nn >> 9] + rank[e]] = nn;
  }
}

// ------ layer-1 agg (+bias+relu) fused with layer-2 GEMM (block MFMA) --------
// Block = 16 nodes. Phase 1: wave wv gathers nodes n0+wv*4+s (s=0..3) with the
// proven depth-2 pipeline; reduced h rows land in a 4.4KB LDS tile. Phase 2:
// 16x128 @ 128x128 MFMA (wave wv owns column tiles 2wv,2wv+1; B fragments read
// straight from L2-hot Wt2), scale by dinv, coalesced store to gB.
// Eliminates hB (25.6MB write + 25.6MB read) and the gemm2 dispatch.
__global__ __launch_bounds__(256) void k_agg_g2(
    const _Float16* __restrict__ g, const float* __restrict__ dinv,
    const int* __restrict__ base, const int* __restrict__ partials,
    const int* __restrict__ ssrc, const float* __restrict__ bias,
    const _Float16* __restrict__ Wt2, _Float16* __restrict__ gB, int N) {
  __shared__ _Float16 As[16][136];
  const int tid = threadIdx.x;
  const int lane = tid & 63;
  const int wv = tid >> 6;
  const int gq = lane >> 4;
  const int l = lane & 15;
  const int n0 = blockIdx.x * 16;

  #pragma unroll 1
  for (int s = 0; s < 4; s++) {
    const int n = n0 + wv * 4 + s;
    if (n < N) {
      const int b0 = base[n] + partials[n >> 9];
      const int b1 = base[n + 1] + partials[(n + 1) >> 9];

      int e = b0;
      int p0 = e + gq, p1 = e + 4 + gq;
      int i0 = ssrc[p0], i1 = ssrc[p1];      // +8 slack makes loads safe
      i0 = (p0 < b1) ? i0 : N;
      i1 = (p1 < b1) ? i1 : N;
      v8hf r0 = *(const v8hf*)(g + (size_t)i0 * NFEAT + l * 8);
      v8hf r1 = *(const v8hf*)(g + (size_t)i1 * NFEAT + l * 8);
      int e2 = e + 8;
      int j0 = N, j1 = N;
      if (e2 < b1) {
        int q0 = e2 + gq, q1 = e2 + 4 + gq;
        j0 = ssrc[q0]; j1 = ssrc[q1];
        j0 = (q0 < b1) ? j0 : N;
        j1 = (q1 < b1) ? j1 : N;
      }

      float acc[8] = {};
      while (true) {
        bool more = (e2 < b1);
        v8hf s0, s1;
        if (more) {                  // issue iter k+1 gathers before consuming k
          s0 = *(const v8hf*)(g + (size_t)j0 * NFEAT + l * 8);
          s1 = *(const v8hf*)(g + (size_t)j1 * NFEAT + l * 8);
        }
        int e3 = e2 + 8;
        int c0 = N, c1 = N;
        if (e3 < b1) {
          int q0 = e3 + gq, q1 = e3 + 4 + gq;
          c0 = ssrc[q0]; c1 = ssrc[q1];
          c0 = (q0 < b1) ? c0 : N;
          c1 = (q1 < b1) ? c1 : N;
        }
        #pragma unroll
        for (int j = 0; j < 8; j++) acc[j] += (float)r0[j] + (float)r1[j];
        if (!more) break;
        r0 = s0; r1 = s1;
        j0 = c0; j1 = c1;
        e2 = e3;
      }

      #pragma unroll
      for (int j = 0; j < 8; j++) {
        acc[j] += __shfl_xor(acc[j], 16, 64);
        acc[j] += __shfl_xor(acc[j], 32, 64);
      }
      if (gq == 0) {
        float dvn = dinv[n];
        const float* bp = bias + l * 8;
        float4 bb0 = *(const float4*)(bp);
        float4 bb1 = *(const float4*)(bp + 4);
        float bv[8] = {bb0.x, bb0.y, bb0.z, bb0.w, bb1.x, bb1.y, bb1.z, bb1.w};
        v8hf o;
        #pragma unroll
        for (int j = 0; j < 8; j++)
          o[j] = (_Float16)fmaxf(acc[j] * dvn + bv[j], 0.f);
        *(v8hf*)&As[wv * 4 + s][l * 8] = o;    // h row -> LDS tile
      }
    }
  }
  __syncthreads();

  // ---- phase 2: D[16][128] = As @ W2 ; wave wv -> column tiles 2wv, 2wv+1
  v4f acc2[2] = {};
  #pragma unroll
  for (int kt = 0; kt < 4; kt++) {
    v8hf af = *(const v8hf*)(&As[l][kt * 32 + gq * 8]);
    #pragma unroll
    for (int c = 0; c < 2; c++) {
      int ct = wv * 2 + c;
      v8hf bf = *(const v8hf*)(Wt2 + (size_t)(ct * 16 + l) * 128 + kt * 32 + gq * 8);
      acc2[c] = __builtin_amdgcn_mfma_f32_16x16x32_f16(af, bf, acc2[c], 0, 0, 0);
    }
  }
  float dv[4];
  #pragma unroll
  for (int r = 0; r < 4; r++) {
    int nd = n0 + gq * 4 + r;
    int c = (nd < N) ? nd : (N - 1);
    dv[r] = dinv[c];
  }
  __syncthreads();                   // all As reads done -> reuse as C tile
  #pragma unroll
  for (int c = 0; c < 2; c++)
    #pragma unroll
    for (int r = 0; r < 4; r++)
      As[gq * 4 + r][(wv * 2 + c) * 16 + l] = (_Float16)(acc2[c][r] * dv[r]);
  __syncthreads();

  int row = tid >> 4, c8 = tid & 15;  // 16 rows x 16 chunks of 16B
  int gr = n0 + row;
  if (gr < N)
    *(v8hf*)(gB + (size_t)gr * NFEAT + c8 * 8) = *(const v8hf*)&As[row][c8 * 8];
}

// ---------------- layer-2 agg fused with final linear ------------------------
__global__ __launch_bounds__(256) void k_agg_final(
    const _Float16* __restrict__ g, const float* __restrict__ dinv,
    const int* __restrict__ base, const int* __restrict__ partials,
    const int* __restrict__ ssrc,
    const float* __restrict__ bias, const float* __restrict__ wlin,
    const float* __restrict__ blin, float* __restrict__ out, int N) {
  const int lane = threadIdx.x & 63;
  const int n = blockIdx.x * 4 + (threadIdx.x >> 6);
  if (n >= N) return;
  const int gq = lane >> 4;
  const int l = lane & 15;
  const int b0 = base[n] + partials[n >> 9];
  const int b1 = base[n + 1] + partials[(n + 1) >> 9];

  int e = b0;
  int p0 = e + gq, p1 = e + 4 + gq;
  int i0 = ssrc[p0], i1 = ssrc[p1];
  i0 = (p0 < b1) ? i0 : N;
  i1 = (p1 < b1) ? i1 : N;
  v8hf r0 = *(const v8hf*)(g + (size_t)i0 * NFEAT + l * 8);
  v8hf r1 = *(const v8hf*)(g + (size_t)i1 * NFEAT + l * 8);
  int e2 = e + 8;
  int j0 = N, j1 = N;
  if (e2 < b1) {
    int q0 = e2 + gq, q1 = e2 + 4 + gq;
    j0 = ssrc[q0]; j1 = ssrc[q1];
    j0 = (q0 < b1) ? j0 : N;
    j1 = (q1 < b1) ? j1 : N;
  }

  float acc[8] = {};
  while (true) {
    bool more = (e2 < b1);
    v8hf s0, s1;
    if (more) {
      s0 = *(const v8hf*)(g + (size_t)j0 * NFEAT + l * 8);
      s1 = *(const v8hf*)(g + (size_t)j1 * NFEAT + l * 8);
    }
    int e3 = e2 + 8;
    int c0 = N, c1 = N;
    if (e3 < b1) {
      int q0 = e3 + gq, q1 = e3 + 4 + gq;
      c0 = ssrc[q0]; c1 = ssrc[q1];
      c0 = (q0 < b1) ? c0 : N;
      c1 = (q1 < b1) ? c1 : N;
    }
    #pragma unroll
    for (int j = 0; j < 8; j++) acc[j] += (float)r0[j] + (float)r1[j];
    if (!more) break;
    r0 = s0; r1 = s1;
    j0 = c0; j1 = c1;
    e2 = e3;
  }

  #pragma unroll
  for (int j = 0; j < 8; j++) {
    acc[j] += __shfl_xor(acc[j], 16, 64);
    acc[j] += __shfl_xor(acc[j], 32, 64);
  }
  float dvn = dinv[n];
  const float* bp = bias + l * 8;
  const float* wp = wlin + l * 8;
  float4 bb0 = *(const float4*)(bp);
  float4 bb1 = *(const float4*)(bp + 4);
  float4 wl0 = *(const float4*)(wp);
  float4 wl1 = *(const float4*)(wp + 4);
  float bv[8] = {bb0.x, bb0.y, bb0.z, bb0.w, bb1.x, bb1.y, bb1.z, bb1.w};
  float wv[8] = {wl0.x, wl0.y, wl0.z, wl0.w, wl1.x, wl1.y, wl1.z, wl1.w};
  float pv = 0.f;
  #pragma unroll
  for (int j = 0; j < 8; j++)
    pv += fmaxf(acc[j] * dvn + bv[j], 0.f) * wv[j];
  pv += __shfl_xor(pv, 1, 64);
  pv += __shfl_xor(pv, 2, 64);
  pv += __shfl_xor(pv, 4, 64);
  pv += __shfl_xor(pv, 8, 64);
  if (lane == 0) out[n] = pv + blin[0];
}

extern "C" void kernel_launch(void* const* d_in, const int* in_sizes, int n_in,
                              void* d_out, int out_size, void* d_ws, size_t ws_size,
                              hipStream_t stream) {
  const float* x    = (const float*)d_in[0];
  const int*   ei   = (const int*)d_in[1];
  const float* W1   = (const float*)d_in[2];
  const float* b1   = (const float*)d_in[3];
  const float* W2   = (const float*)d_in[4];
  const float* b2   = (const float*)d_in[5];
  const float* Wlin = (const float*)d_in[6];
  const float* blin = (const float*)d_in[7];
  const int N = in_sizes[0] / NFEAT;
  const int E = in_sizes[1] / 2;
  const int* src = ei;
  const int* dst = ei + E;
  const int Etot = E + N;   // real edges + self edges

  // workspace layout (4B units)
  int* ws_i = (int*)d_ws;
  size_t off = 0;
  int* deg      = ws_i + off; off += N;
  int* base     = ws_i + off; off += (size_t)N + 1;
  off = (off + 3) & ~(size_t)3;
  int* partials = ws_i + off; off += 256;
  int* ssrc     = ws_i + off; off += Etot + 8;   // +8 slack for tail loads
  float* dinv   = (float*)(ws_i + off); off += N;
  off = (off + 3) & ~(size_t)3;
  _Float16* Wt1 = (_Float16*)(ws_i + off); off += 8192;  // 16384 halves
  _Float16* Wt2 = (_Float16*)(ws_i + off); off += 8192;
  _Float16* gA  = (_Float16*)(ws_i + off); off += (size_t)(N + 1) * 64;  // +sentinel
  _Float16* gB  = (_Float16*)(ws_i + off); off += (size_t)(N + 1) * 64;  // +sentinel
  // rank aliases gB: written by k_deg_rank_w, consumed by k_sg1's scatter half,
  // dead before k_agg_g2 writes gB. Does NOT alias gA (GEMM1 writes gA in k_sg1).
  int* rank = (int*)gB;

  hipMemsetAsync(deg, 0, (size_t)N * sizeof(int), stream);

  const int tpbE = 256;
  const int gE = (Etot + 32768 + tpbE - 1) / tpbE;
  k_deg_rank_w<<<gE, tpbE, 0, stream>>>(dst, deg, rank, E, N, W1, W2, Wt1, Wt2);

  const int nb = (N + 1 + 511) / 512;
  k_scan_blocks<<<nb, 256, 0, stream>>>(deg, base, partials, dinv, N);
  k_scan_partials<<<1, 256, 0, stream>>>(partials, nb);

  const int gg = (N + 63) / 64;
  const int scb = (Etot + 255) / 256;
  // fused: scatter + layer-1 GEMM, interleaved for true overlap
  k_sg1<<<scb + gg, 256, 0, stream>>>(src, dst, rank, base, partials, ssrc,
                                      x, Wt1, dinv, gA, gB, E, N, gg);
  // layer-1 agg fused with layer-2 GEMM -> gB
  const int ga16 = (N + 15) / 16;
  k_agg_g2<<<ga16, 256, 0, stream>>>(gA, dinv, base, partials, ssrc, b1,
                                     Wt2, gB, N);
  // layer-2 agg fused with final linear
  const int ga = (N + 3) / 4;
  k_agg_final<<<ga, 256, 0, stream>>>(gB, dinv, base, partials, ssrc, b2,
                                      Wlin, blin, (float*)d_out, N);
}